// Round 4
// baseline (588.420 us; speedup 1.0000x reference)
//
#include <hip/hip_runtime.h>
#include <hip/hip_bf16.h>
#include <math.h>

#define DIM 2048
#define BATCH 16384

typedef __attribute__((ext_vector_type(8))) short short8;
typedef __attribute__((ext_vector_type(4))) float floatx4;
typedef unsigned short ushort_t;
typedef unsigned int uint_t;

__device__ __forceinline__ ushort_t f2bf(float f) {
    union { float f; unsigned u; } v; v.f = f;
    unsigned r = v.u + 0x7FFFu + ((v.u >> 16) & 1u);   // RNE
    return (ushort_t)(r >> 16);
}

__device__ __forceinline__ uint_t cvt2bf(float a, float b) {
    __hip_bfloat162 h = __float22bfloat162_rn(float2{a, b});   // v_cvt_pk_bf16_f32
    union { __hip_bfloat162 h; uint_t u; } v; v.h = h;
    return v.u;
}

// ---- band scale vector (length DIM) ----
__global__ void k_scale(const float* __restrict__ fw, const float* __restrict__ kp,
                        float* __restrict__ s) {
    int n = blockIdx.x * blockDim.x + threadIdx.x;
    if (n >= DIM) return;
    float kv = kp[0];
    float f = 1.0f;
    for (int i = 0; i < 30; ++i) {
        long s0 = (long)((double)i       * (double)(DIM - 1) / 30.0);
        long e0 = (long)((double)(i + 1) * (double)(DIM - 1) / 30.0);
        if (n >= s0 && n < e0) {
            if (e0 <= 30)
                f = 1.0f + fw[i] * kv * (1.0f - (float)i / 30.0f);
            else
                f = 1.0f - fw[i] * kv * (1.0f - (float)(i - 30) / 30.0f);
        }
    }
    s[n] = f;
}

// ---- DCT matrix + transpose, bf16, exact integer phase reduction ----
__global__ void k_gen_d(ushort_t* __restrict__ D, ushort_t* __restrict__ Dt) {
    int idx = blockIdx.x * blockDim.x + threadIdx.x;   // DIM*DIM
    int r = idx >> 11;
    int c = idx & (DIM - 1);
    const float w  = 7.6699039394282058e-4f;  // pi/4096
    const float s0 = 0.02209708691207961f;    // sqrt(1/2048)
    const float s1 = 0.03125f;                // sqrt(2/2048)
    int m1 = ((2 * c + 1) * r) & (4 * DIM - 1);
    int m2 = ((2 * r + 1) * c) & (4 * DIM - 1);
    float v1 = __cosf(w * (float)m1) * (r == 0 ? s0 : s1);   // arg < 2pi: no reduction needed
    float v2 = __cosf(w * (float)m2) * (c == 0 ? s0 : s1);
    D[idx]  = f2bf(v1);
    Dt[idx] = f2bf(v2);
}

// ---- merged fp32 -> bf16 cast for WEIGHT tensors only (X is fused into G2) ----
#define U_W1   262144
#define U_W2    65536
#define U_WH    16384
__global__ void k_cast_w(const float* __restrict__ W1, const float* __restrict__ W2,
                         const float* __restrict__ Wmu, const float* __restrict__ Wlv,
                         ushort_t* __restrict__ W1bf, ushort_t* __restrict__ W2bf,
                         ushort_t* __restrict__ Wcat) {
    int i = blockIdx.x * blockDim.x + threadIdx.x;
    const float* src; ushort_t* dst; int u;
    if (i < U_W1)                    { src = W1;  dst = W1bf;             u = i; }
    else if (i < U_W1 + U_W2)        { src = W2;  dst = W2bf;             u = i - U_W1; }
    else if (i < U_W1 + U_W2 + U_WH) { src = Wmu; dst = Wcat;             u = i - U_W1 - U_W2; }
    else                             { src = Wlv; dst = Wcat + 8 * U_WH;  u = i - U_W1 - U_W2 - U_WH; }
    const float4* p = reinterpret_cast<const float4*>(src) + 2 * (size_t)u;
    float4 a = p[0], b = p[1];
    short8 r;
    r[0] = (short)f2bf(a.x); r[1] = (short)f2bf(a.y);
    r[2] = (short)f2bf(a.z); r[3] = (short)f2bf(a.w);
    r[4] = (short)f2bf(b.x); r[5] = (short)f2bf(b.y);
    r[6] = (short)f2bf(b.z); r[7] = (short)f2bf(b.w);
    *reinterpret_cast<short8*>(dst + 8 * (size_t)u) = r;
}

// ---- GEMM core: C = A @ B^T (XOR-swizzled B LDS, XCD block map) ----
// AMODE 0: A bf16 via global_load_lds (m97 style)
// AMODE 1: A fp32, fragments loaded DIRECT from global (no LDS), cvt_pk->bf16.
// AMODE 2: A bf16, fragments loaded direct from global (no LDS).
// Direct modes issue A loads between B-DMA issue and barrier2, so the
// compiler's vmcnt(0)-before-barrier drains A and B together (one co-drain).
// EPI 0: *ep0[col] -> bf16 | 1: plain -> bf16 | 2: +ep0[col], relu -> bf16
// EPI 3: +bias (ep0 lo / ep1 hi) -> fp32 split output (mu | logvar)
template<int TM, int TN, int EPI, int AMODE>
__device__ __forceinline__ void gemm_core(
        const ushort_t* __restrict__ A, const float* __restrict__ Af,
        const ushort_t* __restrict__ B,
        ushort_t* __restrict__ Cb, float* __restrict__ Cf,
        const float* __restrict__ ep0, const float* __restrict__ ep1,
        int M, int N, int K) {
    constexpr int BM = 32 * TM;
    constexpr int BN = 32 * TN;
    __shared__ __align__(16) ushort_t As[(AMODE == 0) ? BM * 32 : 4];
    __shared__ __align__(16) ushort_t Bs[BN * 32];

    const int tid  = threadIdx.x;
    const int lane = tid & 63;
    const int wave = tid >> 6;
    const int wm   = wave >> 1;
    const int wn   = wave & 1;
    const int q    = lane >> 4;
    const int l16  = lane & 15;

    const int tilesM = M / BM;
    const int tilesN = N / BN;
    const int bid = (int)blockIdx.x;
    const int xcd = bid & 7;
    const int j   = bid >> 3;
    const int bm  = xcd * (tilesM >> 3) + j / tilesN;
    const int bn  = j % tilesN;

    floatx4 acc[TM][TN];
    #pragma unroll
    for (int i = 0; i < TM; ++i)
        #pragma unroll
        for (int jj = 0; jj < TN; ++jj)
            acc[i][jj] = (floatx4){0.f, 0.f, 0.f, 0.f};

    const long aBase = (long)bm * BM * K;
    const long bBase = (long)bn * BN * K;

    const float*    apf = nullptr;
    const ushort_t* aph = nullptr;
    if constexpr (AMODE == 1) apf = Af + aBase + (long)(wm * TM * 16 + l16) * K + q * 8;
    if constexpr (AMODE == 2) aph = A  + aBase + (long)(wm * TM * 16 + l16) * K + q * 8;

    for (int kt = 0; kt < K; kt += 32) {
        __syncthreads();   // direct modes: nothing in flight here -> no drain stall
        if constexpr (AMODE == 0) {
            #pragma unroll
            for (int i = 0; i < BM / 64; ++i) {
                int idx = tid + i * 256;
                int row = idx >> 2, seg = idx & 3;
                int gseg = seg ^ ((row >> 1) & 3);
                const ushort_t* g = A + aBase + (long)row * K + kt + gseg * 8;
                __builtin_amdgcn_global_load_lds(
                    (const __attribute__((address_space(1))) void*)g,
                    (__attribute__((address_space(3))) void*)(As + idx * 8),
                    16, 0, 0);
            }
        }
        #pragma unroll
        for (int i = 0; i < BN / 64; ++i) {
            int idx = tid + i * 256;
            int row = idx >> 2, seg = idx & 3;
            int gseg = seg ^ ((row >> 1) & 3);
            const ushort_t* g = B + bBase + (long)row * K + kt + gseg * 8;
            __builtin_amdgcn_global_load_lds(
                (const __attribute__((address_space(1))) void*)g,
                (__attribute__((address_space(3))) void*)(Bs + idx * 8),
                16, 0, 0);
        }
        // direct A-fragment loads: in flight across barrier2's drain (co-drained with B DMA)
        float4 fa[TM], fb[TM];
        short8 afd[TM];
        if constexpr (AMODE == 1) {
            #pragma unroll
            for (int t = 0; t < TM; ++t) {
                const float* p = apf + (long)t * 16 * K + kt;
                fa[t] = *reinterpret_cast<const float4*>(p);
                fb[t] = *reinterpret_cast<const float4*>(p + 4);
            }
        } else if constexpr (AMODE == 2) {
            #pragma unroll
            for (int t = 0; t < TM; ++t)
                afd[t] = *reinterpret_cast<const short8*>(aph + (long)t * 16 * K + kt);
        }
        __syncthreads();

        short8 af[TM], bfr[TN];
        if constexpr (AMODE == 0) {
            #pragma unroll
            for (int t = 0; t < TM; ++t) {
                int srow = wm * TM * 16 + t * 16 + l16;
                int rseg = q ^ ((srow >> 1) & 3);
                af[t] = *reinterpret_cast<const short8*>(&As[srow * 32 + rseg * 8]);
            }
        } else if constexpr (AMODE == 1) {
            #pragma unroll
            for (int t = 0; t < TM; ++t) {
                uint_t w0 = cvt2bf(fa[t].x, fa[t].y);
                uint_t w1 = cvt2bf(fa[t].z, fa[t].w);
                uint_t w2 = cvt2bf(fb[t].x, fb[t].y);
                uint_t w3 = cvt2bf(fb[t].z, fb[t].w);
                af[t][0] = (short)(w0 & 0xFFFF); af[t][1] = (short)(w0 >> 16);
                af[t][2] = (short)(w1 & 0xFFFF); af[t][3] = (short)(w1 >> 16);
                af[t][4] = (short)(w2 & 0xFFFF); af[t][5] = (short)(w2 >> 16);
                af[t][6] = (short)(w3 & 0xFFFF); af[t][7] = (short)(w3 >> 16);
            }
        } else {
            #pragma unroll
            for (int t = 0; t < TM; ++t) af[t] = afd[t];
        }
        #pragma unroll
        for (int t = 0; t < TN; ++t) {
            int srow = wn * TN * 16 + t * 16 + l16;
            int rseg = q ^ ((srow >> 1) & 3);
            bfr[t] = *reinterpret_cast<const short8*>(&Bs[srow * 32 + rseg * 8]);
        }
        #pragma unroll
        for (int i = 0; i < TM; ++i)
            #pragma unroll
            for (int jj = 0; jj < TN; ++jj)
                acc[i][jj] = __builtin_amdgcn_mfma_f32_16x16x32_bf16(
                    af[i], bfr[jj], acc[i][jj], 0, 0, 0);
    }

    #pragma unroll
    for (int i = 0; i < TM; ++i) {
        #pragma unroll
        for (int jj = 0; jj < TN; ++jj) {
            #pragma unroll
            for (int r = 0; r < 4; ++r) {
                int row = bm * BM + wm * TM * 16 + i * 16 + q * 4 + r;
                int col = bn * BN + wn * TN * 16 + jj * 16 + l16;
                float v = acc[i][jj][r];
                if constexpr (EPI == 0) {
                    Cb[(long)row * N + col] = f2bf(v * ep0[col]);
                } else if constexpr (EPI == 1) {
                    Cb[(long)row * N + col] = f2bf(v);
                } else if constexpr (EPI == 2) {
                    v += ep0[col];
                    v = v > 0.f ? v : 0.f;
                    Cb[(long)row * N + col] = f2bf(v);
                } else {
                    const int half = N >> 1;
                    if (col < half)
                        Cf[(long)row * half + col] = v + ep0[col];
                    else
                        Cf[(long)M * half + (long)row * half + (col - half)] = v + ep1[col - half];
                }
            }
        }
    }
}

// distinctly-named wrappers so rocprof resolves per-stage durations
__global__ __launch_bounds__(256) void g0_w1d(const ushort_t* A, const ushort_t* B,
        ushort_t* Cb, const float* ep0, int M, int N, int K) {
    gemm_core<2, 2, 0, 0>(A, nullptr, B, Cb, nullptr, ep0, nullptr, M, N, K);
}
__global__ __launch_bounds__(256) void g1_m1(const ushort_t* A, const ushort_t* B,
        ushort_t* Cb, int M, int N, int K) {
    gemm_core<2, 2, 1, 0>(A, nullptr, B, Cb, nullptr, nullptr, nullptr, M, N, K);
}
__global__ __launch_bounds__(256) void g2_xm1(const float* Af, const ushort_t* B,
        ushort_t* Cb, const float* ep0, int M, int N, int K) {
    gemm_core<4, 4, 2, 1>(nullptr, Af, B, Cb, nullptr, ep0, nullptr, M, N, K);
}
__global__ __launch_bounds__(256) void g3_h2(const ushort_t* A, const ushort_t* B,
        ushort_t* Cb, const float* ep0, int M, int N, int K) {
    gemm_core<4, 4, 2, 2>(A, nullptr, B, Cb, nullptr, ep0, nullptr, M, N, K);
}
__global__ __launch_bounds__(256) void g4_head(const ushort_t* A, const ushort_t* B,
        float* Cf, const float* ep0, const float* ep1, int M, int N, int K) {
    gemm_core<4, 4, 3, 2>(A, nullptr, B, nullptr, Cf, ep0, ep1, M, N, K);
}

extern "C" void kernel_launch(void* const* d_in, const int* in_sizes, int n_in,
                              void* d_out, int out_size, void* d_ws, size_t ws_size,
                              hipStream_t stream) {
    const float* x   = (const float*)d_in[0];
    const float* fw  = (const float*)d_in[1];
    const float* kp  = (const float*)d_in[2];
    const float* W1  = (const float*)d_in[3];
    const float* b1  = (const float*)d_in[4];
    const float* W2  = (const float*)d_in[5];
    const float* b2  = (const float*)d_in[6];
    const float* Wmu = (const float*)d_in[7];
    const float* bmu = (const float*)d_in[8];
    const float* Wlv = (const float*)d_in[9];
    const float* blv = (const float*)d_in[10];
    float* out = (float*)d_out;

    char* ws = (char*)d_ws;
    const size_t MB = 1024 * 1024;
    // [W1bf|Dbf|Dtbf|T1sT] (0..24MB) all dead before H1 (0..32MB) is written.
    ushort_t* W1bf = (ushort_t*)(ws + 0);        //  4 MB
    ushort_t* Dbf  = (ushort_t*)(ws + 4  * MB);  //  8 MB
    ushort_t* Dtbf = (ushort_t*)(ws + 12 * MB);  //  8 MB
    ushort_t* T1sT = (ushort_t*)(ws + 20 * MB);  //  4 MB
    ushort_t* H1   = (ushort_t*)(ws + 0);        // 32 MB (overlays the above)
    ushort_t* H2   = (ushort_t*)(ws + 32 * MB);  // 16 MB
    ushort_t* M1T  = (ushort_t*)(ws + 48 * MB);  //  4 MB
    ushort_t* W2bf = (ushort_t*)(ws + 52 * MB);  //  1 MB
    ushort_t* Wcat = (ushort_t*)(ws + 53 * MB);  // 0.5 MB
    float*    svec = (float*)   (ws + 54 * MB);  //  8 KB   (total 55 MB)

    hipLaunchKernelGGL(k_scale, dim3(DIM / 256), dim3(256), 0, stream, fw, kp, svec);
    hipLaunchKernelGGL(k_gen_d, dim3(DIM * DIM / 256), dim3(256), 0, stream, Dbf, Dtbf);
    hipLaunchKernelGGL(k_cast_w, dim3((U_W1 + U_W2 + 2 * U_WH) / 256), dim3(256), 0, stream,
                       W1, W2, Wmu, Wlv, W1bf, W2bf, Wcat);

    // G0: T1sT[j][k] = s[k] * sum_n W1[j][n] * D[k][n]   (1024 x 2048, K=2048)
    hipLaunchKernelGGL(g0_w1d, dim3((1024 / 64) * (2048 / 64)), dim3(256), 0, stream,
                       W1bf, Dbf, T1sT, svec, 1024, 2048, 2048);
    // G1: M1T[j][n] = sum_k T1sT[j][k] * Dt[n][k]        (1024 x 2048, K=2048)
    hipLaunchKernelGGL(g1_m1, dim3((1024 / 64) * (2048 / 64)), dim3(256), 0, stream,
                       T1sT, Dtbf, M1T, 1024, 2048, 2048);
    // G2: H1 = relu(X_fp32 @ M1 + b1)                     (16384 x 1024, K=2048)
    hipLaunchKernelGGL(g2_xm1, dim3((BATCH / 128) * (1024 / 128)), dim3(256), 0, stream,
                       x, M1T, H1, b1, BATCH, 1024, 2048);
    // G3: H2 = relu(H1 @ W2^T + b2)                       (16384 x 512, K=1024)
    hipLaunchKernelGGL(g3_h2, dim3((BATCH / 128) * (512 / 128)), dim3(256), 0, stream,
                       H1, W2bf, H2, b2, BATCH, 512, 1024);
    // G4: [mu | logvar] = H2 @ Wcat^T + bias, fp32 split   (16384 x 512, K=512)
    hipLaunchKernelGGL(g4_head, dim3((BATCH / 128) * (512 / 128)), dim3(256), 0, stream,
                       H2, Wcat, out, bmu, blv, BATCH, 512, 512);

    (void)in_sizes; (void)n_in; (void)out_size; (void)ws_size;
}

// Round 5
// 406.223 us; speedup vs baseline: 1.4485x; 1.4485x over previous
//
#include <hip/hip_runtime.h>
#include <hip/hip_bf16.h>
#include <math.h>

#define DIM 2048
#define BATCH 16384

typedef __attribute__((ext_vector_type(8))) short short8;
typedef __attribute__((ext_vector_type(4))) short short4v;
typedef __attribute__((ext_vector_type(4))) float floatx4;
typedef unsigned short ushort_t;

__device__ __forceinline__ ushort_t f2bf(float f) {
    union { float f; unsigned u; } v; v.f = f;
    unsigned r = v.u + 0x7FFFu + ((v.u >> 16) & 1u);   // RNE
    return (ushort_t)(r >> 16);
}

// ---- band scale vector (length DIM) ----
__global__ void k_scale(const float* __restrict__ fw, const float* __restrict__ kp,
                        float* __restrict__ s) {
    int n = blockIdx.x * blockDim.x + threadIdx.x;
    if (n >= DIM) return;
    float kv = kp[0];
    float f = 1.0f;
    for (int i = 0; i < 30; ++i) {
        long s0 = (long)((double)i       * (double)(DIM - 1) / 30.0);
        long e0 = (long)((double)(i + 1) * (double)(DIM - 1) / 30.0);
        if (n >= s0 && n < e0) {
            if (e0 <= 30)
                f = 1.0f + fw[i] * kv * (1.0f - (float)i / 30.0f);
            else
                f = 1.0f - fw[i] * kv * (1.0f - (float)(i - 30) / 30.0f);
        }
    }
    s[n] = f;
}

// ---- DCT matrix + transpose, bf16, exact integer phase reduction ----
__global__ void k_gen_d(ushort_t* __restrict__ D, ushort_t* __restrict__ Dt) {
    int idx = blockIdx.x * blockDim.x + threadIdx.x;   // DIM*DIM
    int r = idx >> 11;
    int c = idx & (DIM - 1);
    const float w  = 7.6699039394282058e-4f;  // pi/4096
    const float s0 = 0.02209708691207961f;    // sqrt(1/2048)
    const float s1 = 0.03125f;                // sqrt(2/2048)
    int m1 = ((2 * c + 1) * r) & (4 * DIM - 1);
    int m2 = ((2 * r + 1) * c) & (4 * DIM - 1);
    float v1 = __cosf(w * (float)m1) * (r == 0 ? s0 : s1);   // arg < 2pi
    float v2 = __cosf(w * (float)m2) * (c == 0 ? s0 : s1);
    D[idx]  = f2bf(v1);
    Dt[idx] = f2bf(v2);
}

// ---- fp32 -> bf16 casts ----
#define U_W1   262144
#define U_W2    65536
#define U_WH    16384
__global__ void k_cast_w(const float* __restrict__ W1, const float* __restrict__ W2,
                         const float* __restrict__ Wmu, const float* __restrict__ Wlv,
                         ushort_t* __restrict__ W1bf, ushort_t* __restrict__ W2bf,
                         ushort_t* __restrict__ Wcat) {
    int i = blockIdx.x * blockDim.x + threadIdx.x;
    const float* src; ushort_t* dst; int u;
    if (i < U_W1)                    { src = W1;  dst = W1bf;             u = i; }
    else if (i < U_W1 + U_W2)        { src = W2;  dst = W2bf;             u = i - U_W1; }
    else if (i < U_W1 + U_W2 + U_WH) { src = Wmu; dst = Wcat;             u = i - U_W1 - U_W2; }
    else                             { src = Wlv; dst = Wcat + 8 * U_WH;  u = i - U_W1 - U_W2 - U_WH; }
    const float4* p = reinterpret_cast<const float4*>(src) + 2 * (size_t)u;
    float4 a = p[0], b = p[1];
    short8 r;
    r[0] = (short)f2bf(a.x); r[1] = (short)f2bf(a.y);
    r[2] = (short)f2bf(a.z); r[3] = (short)f2bf(a.w);
    r[4] = (short)f2bf(b.x); r[5] = (short)f2bf(b.y);
    r[6] = (short)f2bf(b.z); r[7] = (short)f2bf(b.w);
    *reinterpret_cast<short8*>(dst + 8 * (size_t)u) = r;
}

__global__ void k_cast_x(const float* __restrict__ in, ushort_t* __restrict__ out) {
    int i = blockIdx.x * blockDim.x + threadIdx.x;
    const float4* p = reinterpret_cast<const float4*>(in) + 2 * (size_t)i;
    float4 a = p[0], b = p[1];
    short8 r;
    r[0] = (short)f2bf(a.x); r[1] = (short)f2bf(a.y);
    r[2] = (short)f2bf(a.z); r[3] = (short)f2bf(a.w);
    r[4] = (short)f2bf(b.x); r[5] = (short)f2bf(b.y);
    r[6] = (short)f2bf(b.z); r[7] = (short)f2bf(b.w);
    *reinterpret_cast<short8*>(out + 8 * (size_t)i) = r;
}

// ---- split-K reduce: out = bf16( (P0+P1+P2+P3) [* scale[col]] ) ----
__global__ void k_red(const float* __restrict__ P, ushort_t* __restrict__ out,
                      const float* __restrict__ scale, int n4, int n4row) {
    int i = blockIdx.x * blockDim.x + threadIdx.x;   // float4 index
    const float4* p = reinterpret_cast<const float4*>(P);
    float4 a = p[i], b = p[i + n4], c = p[i + 2 * n4], d = p[i + 3 * n4];
    float4 s;
    s.x = a.x + b.x + c.x + d.x;
    s.y = a.y + b.y + c.y + d.y;
    s.z = a.z + b.z + c.z + d.z;
    s.w = a.w + b.w + c.w + d.w;
    if (scale) {
        float4 sc = reinterpret_cast<const float4*>(scale)[i & (n4row - 1)];
        s.x *= sc.x; s.y *= sc.y; s.z *= sc.z; s.w *= sc.w;
    }
    short4v o;
    o[0] = (short)f2bf(s.x); o[1] = (short)f2bf(s.y);
    o[2] = (short)f2bf(s.z); o[3] = (short)f2bf(s.w);
    *reinterpret_cast<short4v*>(out + 4 * (size_t)i) = o;
}

// ---- GEMM core: C = A @ B^T, all-DMA staging (proven R2 structure) ----
// BK in {32,64}; XOR segment swizzle keeps LDS conflict-free for both.
// SK4: grid = tiles*4, each block does K-chunk [sk*KC, sk*KC+KC) -> fp32 partial (EPI 4).
// EPI 0: *ep0[col]->bf16 | 1: plain->bf16 | 2: +ep0[col],relu->bf16
// EPI 3: +bias split fp32 (mu|logvar) | 4: fp32 partial to Cf + sk*M*N
template<int TM, int TN, int BK, int EPI, bool SK4>
__device__ __forceinline__ void gemm_core(
        const ushort_t* __restrict__ A, const ushort_t* __restrict__ B,
        ushort_t* __restrict__ Cb, float* __restrict__ Cf,
        const float* __restrict__ ep0, const float* __restrict__ ep1,
        int M, int N, int K, int KC) {
    constexpr int BM = 32 * TM;
    constexpr int BN = 32 * TN;
    constexpr int SEGS = BK / 8;              // 16B segments per row
    constexpr int RSH  = (BK == 32) ? 1 : 0;  // swizzle period: 128B / rowbytes
    constexpr int SSH  = (SEGS == 4) ? 2 : 3;
    __shared__ __align__(16) ushort_t As[BM * BK];
    __shared__ __align__(16) ushort_t Bs[BN * BK];

    const int tid  = threadIdx.x;
    const int lane = tid & 63;
    const int wave = tid >> 6;
    const int wm   = wave >> 1;
    const int wn   = wave & 1;
    const int q    = lane >> 4;
    const int l16  = lane & 15;

    const int tilesM = M / BM;
    const int tilesN = N / BN;
    int bid = (int)blockIdx.x;
    int sk = 0;
    if constexpr (SK4) { int nt = tilesM * tilesN; sk = bid / nt; bid = bid % nt; }
    const int xcd = bid & 7;
    const int j   = bid >> 3;
    const int bm  = xcd * (tilesM >> 3) + j / tilesN;
    const int bn  = j % tilesN;

    floatx4 acc[TM][TN];
    #pragma unroll
    for (int i = 0; i < TM; ++i)
        #pragma unroll
        for (int jj = 0; jj < TN; ++jj)
            acc[i][jj] = (floatx4){0.f, 0.f, 0.f, 0.f};

    const long aBase = (long)bm * BM * K + (long)sk * KC;
    const long bBase = (long)bn * BN * K + (long)sk * KC;
    const int  KLOOP = SK4 ? KC : K;

    for (int kt = 0; kt < KLOOP; kt += BK) {
        __syncthreads();
        #pragma unroll
        for (int i = 0; i < BM * BK / 2048; ++i) {
            int idx = tid + i * 256;
            int row = idx >> SSH, seg = idx & (SEGS - 1);
            int gseg = seg ^ ((row >> RSH) & (SEGS - 1));
            const ushort_t* g = A + aBase + (long)row * K + kt + gseg * 8;
            __builtin_amdgcn_global_load_lds(
                (const __attribute__((address_space(1))) void*)g,
                (__attribute__((address_space(3))) void*)(As + idx * 8),
                16, 0, 0);
        }
        #pragma unroll
        for (int i = 0; i < BN * BK / 2048; ++i) {
            int idx = tid + i * 256;
            int row = idx >> SSH, seg = idx & (SEGS - 1);
            int gseg = seg ^ ((row >> RSH) & (SEGS - 1));
            const ushort_t* g = B + bBase + (long)row * K + kt + gseg * 8;
            __builtin_amdgcn_global_load_lds(
                (const __attribute__((address_space(1))) void*)g,
                (__attribute__((address_space(3))) void*)(Bs + idx * 8),
                16, 0, 0);
        }
        __syncthreads();

        #pragma unroll
        for (int ks = 0; ks < BK / 32; ++ks) {
            short8 af[TM], bfr[TN];
            #pragma unroll
            for (int t = 0; t < TM; ++t) {
                int srow = wm * TM * 16 + t * 16 + l16;
                int rseg = (ks * 4 + q) ^ ((srow >> RSH) & (SEGS - 1));
                af[t] = *reinterpret_cast<const short8*>(&As[srow * BK + rseg * 8]);
            }
            #pragma unroll
            for (int t = 0; t < TN; ++t) {
                int srow = wn * TN * 16 + t * 16 + l16;
                int rseg = (ks * 4 + q) ^ ((srow >> RSH) & (SEGS - 1));
                bfr[t] = *reinterpret_cast<const short8*>(&Bs[srow * BK + rseg * 8]);
            }
            #pragma unroll
            for (int i = 0; i < TM; ++i)
                #pragma unroll
                for (int jj = 0; jj < TN; ++jj)
                    acc[i][jj] = __builtin_amdgcn_mfma_f32_16x16x32_bf16(
                        af[i], bfr[jj], acc[i][jj], 0, 0, 0);
        }
    }

    #pragma unroll
    for (int i = 0; i < TM; ++i) {
        #pragma unroll
        for (int jj = 0; jj < TN; ++jj) {
            #pragma unroll
            for (int r = 0; r < 4; ++r) {
                int row = bm * BM + wm * TM * 16 + i * 16 + q * 4 + r;
                int col = bn * BN + wn * TN * 16 + jj * 16 + l16;
                float v = acc[i][jj][r];
                if constexpr (EPI == 0) {
                    Cb[(long)row * N + col] = f2bf(v * ep0[col]);
                } else if constexpr (EPI == 1) {
                    Cb[(long)row * N + col] = f2bf(v);
                } else if constexpr (EPI == 2) {
                    v += ep0[col];
                    v = v > 0.f ? v : 0.f;
                    Cb[(long)row * N + col] = f2bf(v);
                } else if constexpr (EPI == 3) {
                    const int half = N >> 1;
                    if (col < half)
                        Cf[(long)row * half + col] = v + ep0[col];
                    else
                        Cf[(long)M * half + (long)row * half + (col - half)] = v + ep1[col - half];
                } else {
                    Cf[(long)sk * M * N + (long)row * N + col] = v;
                }
            }
        }
    }
}

// named wrappers (rocprof per-stage attribution)
__global__ __launch_bounds__(256) void g0p_sk(const ushort_t* A, const ushort_t* B,
        float* P, int M, int N, int K, int KC) {
    gemm_core<4, 4, 32, 4, true>(A, B, nullptr, P, nullptr, nullptr, M, N, K, KC);
}
__global__ __launch_bounds__(256) void g1p_sk(const ushort_t* A, const ushort_t* B,
        float* P, int M, int N, int K, int KC) {
    gemm_core<4, 4, 32, 4, true>(A, B, nullptr, P, nullptr, nullptr, M, N, K, KC);
}
__global__ __launch_bounds__(256) void g2_xm1(const ushort_t* A, const ushort_t* B,
        ushort_t* Cb, const float* ep0, int M, int N, int K) {
    gemm_core<4, 4, 64, 2, false>(A, B, Cb, nullptr, ep0, nullptr, M, N, K, 0);
}
__global__ __launch_bounds__(256) void g3_h2(const ushort_t* A, const ushort_t* B,
        ushort_t* Cb, const float* ep0, int M, int N, int K) {
    gemm_core<4, 4, 32, 2, false>(A, B, Cb, nullptr, ep0, nullptr, M, N, K, 0);
}
__global__ __launch_bounds__(256) void g4_head(const ushort_t* A, const ushort_t* B,
        float* Cf, const float* ep0, const float* ep1, int M, int N, int K) {
    gemm_core<4, 4, 32, 3, false>(A, B, nullptr, Cf, ep0, ep1, M, N, K, 0);
}

extern "C" void kernel_launch(void* const* d_in, const int* in_sizes, int n_in,
                              void* d_out, int out_size, void* d_ws, size_t ws_size,
                              hipStream_t stream) {
    const float* x   = (const float*)d_in[0];
    const float* fw  = (const float*)d_in[1];
    const float* kp  = (const float*)d_in[2];
    const float* W1  = (const float*)d_in[3];
    const float* b1  = (const float*)d_in[4];
    const float* W2  = (const float*)d_in[5];
    const float* b2  = (const float*)d_in[6];
    const float* Wmu = (const float*)d_in[7];
    const float* bmu = (const float*)d_in[8];
    const float* Wlv = (const float*)d_in[9];
    const float* blv = (const float*)d_in[10];
    float* out = (float*)d_out;

    char* ws = (char*)d_ws;
    const size_t MB = 1024 * 1024;
    // timeline-safe overlays (total 118.01 MB, within proven R0 footprint):
    ushort_t* W1bf = (ushort_t*)(ws + 0);         //  4 MB   dead after g0p
    ushort_t* Dbf  = (ushort_t*)(ws + 4   * MB);  //  8 MB   dead after g0p
    ushort_t* Dtbf = (ushort_t*)(ws + 12  * MB);  //  8 MB   dead after g1p
    ushort_t* T1sT = (ushort_t*)(ws + 20  * MB);  //  4 MB   dead after g1p
    ushort_t* H1   = (ushort_t*)(ws + 0);         // 32 MB   written by g2 (overlays above)
    float*    P    = (float*)   (ws + 32  * MB);  // 32 MB   dead after k_red #2
    ushort_t* Xbf  = (ushort_t*)(ws + 32  * MB);  // 64 MB   written after P dead (32..96)
    ushort_t* H2   = (ushort_t*)(ws + 96  * MB);  // 16 MB
    ushort_t* M1T  = (ushort_t*)(ws + 112 * MB);  //  4 MB
    ushort_t* W2bf = (ushort_t*)(ws + 116 * MB);  //  1 MB
    ushort_t* Wcat = (ushort_t*)(ws + 117 * MB);  // 0.5 MB
    float*    svec = (float*)   (ws + 118 * MB);  //  8 KB

    hipLaunchKernelGGL(k_scale, dim3(DIM / 256), dim3(256), 0, stream, fw, kp, svec);
    hipLaunchKernelGGL(k_gen_d, dim3(DIM * DIM / 256), dim3(256), 0, stream, Dbf, Dtbf);
    hipLaunchKernelGGL(k_cast_w, dim3((U_W1 + U_W2 + 2 * U_WH) / 256), dim3(256), 0, stream,
                       W1, W2, Wmu, Wlv, W1bf, W2bf, Wcat);

    // G0 (split-K=4): P[sk] = W1bf @ Dbf^T chunk   (1024 x 2048, KC=512)
    hipLaunchKernelGGL(g0p_sk, dim3(8 * 16 * 4), dim3(256), 0, stream,
                       W1bf, Dbf, P, 1024, 2048, 2048, 512);
    // reduce + scale -> T1sT
    hipLaunchKernelGGL(k_red, dim3(1024 * 2048 / 4 / 256), dim3(256), 0, stream,
                       P, T1sT, svec, 1024 * 2048 / 4, 2048 / 4);
    // G1 (split-K=4): P[sk] = T1sT @ Dtbf^T chunk  (1024 x 2048, KC=512)
    hipLaunchKernelGGL(g1p_sk, dim3(8 * 16 * 4), dim3(256), 0, stream,
                       T1sT, Dtbf, P, 1024, 2048, 2048, 512);
    // reduce -> M1T
    hipLaunchKernelGGL(k_red, dim3(1024 * 2048 / 4 / 256), dim3(256), 0, stream,
                       P, M1T, nullptr, 1024 * 2048 / 4, 2048 / 4);

    // X cast (after P is dead; Xbf overlays P region)
    hipLaunchKernelGGL(k_cast_x, dim3(BATCH * DIM / 8 / 256), dim3(256), 0, stream, x, Xbf);

    // G2: H1 = relu(Xbf @ M1 + b1)   (16384 x 1024, K=2048, BK=64 experiment)
    hipLaunchKernelGGL(g2_xm1, dim3((BATCH / 128) * (1024 / 128)), dim3(256), 0, stream,
                       Xbf, M1T, H1, b1, BATCH, 1024, 2048);
    // G3: H2 = relu(H1 @ W2^T + b2)  (16384 x 512, K=1024)
    hipLaunchKernelGGL(g3_h2, dim3((BATCH / 128) * (512 / 128)), dim3(256), 0, stream,
                       H1, W2bf, H2, b2, BATCH, 512, 1024);
    // G4: [mu | logvar] = H2 @ Wcat^T + bias, fp32 split (16384 x 512, K=512)
    hipLaunchKernelGGL(g4_head, dim3((BATCH / 128) * (512 / 128)), dim3(256), 0, stream,
                       H2, Wcat, out, bmu, blv, BATCH, 512, 512);

    (void)in_sizes; (void)n_in; (void)out_size; (void)ws_size;
}